// Round 1
// baseline (1577.835 us; speedup 1.0000x reference)
//
#include <hip/hip_runtime.h>
#include <hip/hip_bf16.h>
#include <math.h>

#define N_NODES 227328
#define H_DIM 128
#define NB_ 111
#define P_ 40
#define MAXLEN_ 10
#define NSTART_ 5
#define NH (N_NODES * H_DIM)

// ---------------- small utility kernels ----------------

__global__ __launch_bounds__(256) void k_zero_stats(float* wsf) {
    int t = threadIdx.x;
    for (int i = t; i < 1024; i += 256) wsf[i] = 0.f;
}

// agg = eps * v
__global__ __launch_bounds__(256) void k_init(const float4* __restrict__ v4,
                                              const float* __restrict__ epsp,
                                              float4* __restrict__ out4, int n4) {
    float eps = epsp[0];
    int stride = gridDim.x * blockDim.x;
    for (int i = blockIdx.x * blockDim.x + threadIdx.x; i < n4; i += stride) {
        float4 a = v4[i];
        out4[i] = make_float4(eps * a.x, eps * a.y, eps * a.z, eps * a.w);
    }
}

// agg[row[e]] += v[col[e]]  — one wave per edge, float2 per lane
__global__ __launch_bounds__(256) void k_scatter(const float* __restrict__ v,
                                                 const int* __restrict__ erow,
                                                 const int* __restrict__ ecol,
                                                 float* agg, int E) {
    int tid = blockIdx.x * blockDim.x + threadIdx.x;
    int lane = tid & 63;
    int wave = tid >> 6;
    int nwaves = (gridDim.x * blockDim.x) >> 6;
    for (int e = wave; e < E; e += nwaves) {
        int r = erow[e], c = ecol[e];
        const float2 val = *((const float2*)(v + (size_t)c * H_DIM) + lane);
        float* dst = agg + (size_t)r * H_DIM + lane * 2;
        unsafeAtomicAdd(dst, val.x);
        unsafeAtomicAdd(dst + 1, val.y);
    }
}

// ---------------- GEMM (in-place safe): C = [bn_relu?](A) @ W + bias ----------------
// 128 rows x 128 cols per block, 256 threads, 8x8 micro-tile.
// Also accumulates per-column sum / sumsq of the OUTPUT (pre-bn) into ws.
__global__ __launch_bounds__(256) void k_gemm(const float* A, float* C,
        const float* __restrict__ W, const float* __restrict__ bias,
        const float* __restrict__ mean, const float* __restrict__ scl,
        const float* __restrict__ beta,
        float* __restrict__ sums, float* __restrict__ sumsq, int applyBN) {
    __shared__ float A_s[128 * 132];
    __shared__ float W_s[128 * 132];
    const int t = threadIdx.x;
    const int tx = t & 15;   // col lane: c = tx + 16*ci  (stride-1 across lanes)
    const int ty = t >> 4;   // row group: r = ty + 16*ri
    const size_t row0 = (size_t)blockIdx.x * 128;

    for (int i = t * 4; i < 128 * 128; i += 1024) {
        float4 w4 = *(const float4*)(W + i);
        int k = i >> 7, c = i & 127;
        *(float4*)(W_s + k * 132 + c) = w4;
    }
    for (int i = t * 4; i < 128 * 128; i += 1024) {
        float4 a4 = *(const float4*)(A + row0 * 128 + i);
        int r = i >> 7, c = i & 127;
        if (applyBN) {
            a4.x = fmaxf(fmaf(a4.x - mean[c + 0], scl[c + 0], beta[c + 0]), 0.f);
            a4.y = fmaxf(fmaf(a4.y - mean[c + 1], scl[c + 1], beta[c + 1]), 0.f);
            a4.z = fmaxf(fmaf(a4.z - mean[c + 2], scl[c + 2], beta[c + 2]), 0.f);
            a4.w = fmaxf(fmaf(a4.w - mean[c + 3], scl[c + 3], beta[c + 3]), 0.f);
        }
        *(float4*)(A_s + r * 132 + c) = a4;
    }
    __syncthreads();

    float acc[8][8];
#pragma unroll
    for (int ri = 0; ri < 8; ri++)
#pragma unroll
        for (int ci = 0; ci < 8; ci++) acc[ri][ci] = 0.f;

#pragma unroll 4
    for (int k = 0; k < 128; k++) {
        float a[8], w[8];
#pragma unroll
        for (int ri = 0; ri < 8; ri++) a[ri] = A_s[(ty + 16 * ri) * 132 + k];
#pragma unroll
        for (int ci = 0; ci < 8; ci++) w[ci] = W_s[k * 132 + tx + 16 * ci];
#pragma unroll
        for (int ri = 0; ri < 8; ri++)
#pragma unroll
            for (int ci = 0; ci < 8; ci++)
                acc[ri][ci] = fmaf(a[ri], w[ci], acc[ri][ci]);
    }

    float s[8], s2[8];
#pragma unroll
    for (int ci = 0; ci < 8; ci++) { s[ci] = 0.f; s2[ci] = 0.f; }
#pragma unroll
    for (int ci = 0; ci < 8; ci++) {
        int c = tx + 16 * ci;
        float b = bias[c];
#pragma unroll
        for (int ri = 0; ri < 8; ri++) {
            int r = ty + 16 * ri;
            float val = acc[ri][ci] + b;
            C[(row0 + r) * H_DIM + c] = val;
            s[ci] += val;
            s2[ci] += val * val;
        }
    }
    __syncthreads();
    float* red = A_s;  // reuse as [c][ty][2]
#pragma unroll
    for (int ci = 0; ci < 8; ci++) {
        int c = tx + 16 * ci;
        red[(c * 16 + ty) * 2 + 0] = s[ci];
        red[(c * 16 + ty) * 2 + 1] = s2[ci];
    }
    __syncthreads();
    if (t < 128) {
        float S = 0.f, S2 = 0.f;
#pragma unroll
        for (int j = 0; j < 16; j++) {
            S += red[(t * 16 + j) * 2];
            S2 += red[(t * 16 + j) * 2 + 1];
        }
        unsafeAtomicAdd(sums + t, S);
        unsafeAtomicAdd(sumsq + t, S2);
    }
}

__global__ void k_finalize(const float* __restrict__ sums, const float* __restrict__ sumsq,
                           float* __restrict__ mean, float* __restrict__ scl,
                           const float* __restrict__ g, float invN) {
    int t = threadIdx.x;
    if (t < H_DIM) {
        float m = sums[t] * invN;
        float var = sumsq[t] * invN - m * m;
        mean[t] = m;
        scl[t] = g[t] * rsqrtf(var + 1e-5f);
    }
}

__global__ __launch_bounds__(256) void k_bnrelu(float4* y4, const float* __restrict__ mean,
                                                const float* __restrict__ scl,
                                                const float* __restrict__ beta, int n4) {
    int stride = gridDim.x * blockDim.x;
    for (int i = blockIdx.x * blockDim.x + threadIdx.x; i < n4; i += stride) {
        int c = (i & 31) * 4;
        float4 a = y4[i];
        a.x = fmaxf(fmaf(a.x - mean[c + 0], scl[c + 0], beta[c + 0]), 0.f);
        a.y = fmaxf(fmaf(a.y - mean[c + 1], scl[c + 1], beta[c + 1]), 0.f);
        a.z = fmaxf(fmaf(a.z - mean[c + 2], scl[c + 2], beta[c + 2]), 0.f);
        a.w = fmaxf(fmaf(a.w - mean[c + 3], scl[c + 3], beta[c + 3]), 0.f);
        y4[i] = a;
    }
}

// ---------------- random walk (tiny, one block) ----------------

__device__ inline float block_max_f(float v, int t, float* s_r) {
#pragma unroll
    for (int m = 1; m < 64; m <<= 1) v = fmaxf(v, __shfl_xor(v, m, 64));
    if ((t & 63) == 0) s_r[t >> 6] = v;
    __syncthreads();
    float r = fmaxf(s_r[0], s_r[1]);
    __syncthreads();
    return r;
}

__device__ inline float block_sum_f(float v, int t, float* s_r) {
#pragma unroll
    for (int m = 1; m < 64; m <<= 1) v += __shfl_xor(v, m, 64);
    if ((t & 63) == 0) s_r[t >> 6] = v;
    __syncthreads();
    float r = s_r[0] + s_r[1];
    __syncthreads();
    return r;
}

// argmax, ties -> smaller index (matches jnp.argmax)
__device__ inline void block_argmax(float v, int idx, int t, float* s_rv, int* s_ri,
                                    float* outv, int* outi) {
#pragma unroll
    for (int m = 1; m < 64; m <<= 1) {
        float ov = __shfl_xor(v, m, 64);
        int oi = __shfl_xor(idx, m, 64);
        if (ov > v || (ov == v && oi < idx)) { v = ov; idx = oi; }
    }
    if ((t & 63) == 0) { s_rv[t >> 6] = v; s_ri[t >> 6] = idx; }
    __syncthreads();
    float v0 = s_rv[0], v1 = s_rv[1];
    int i0 = s_ri[0], i1 = s_ri[1];
    if (v1 > v0 || (v1 == v0 && i1 < i0)) { *outv = v1; *outi = i1; }
    else { *outv = v0; *outi = i0; }
    __syncthreads();
}

__global__ __launch_bounds__(128) void k_walk(const int* __restrict__ adj,
        const float* __restrict__ scores, const float* __restrict__ feats,
        const int* __restrict__ perm, const float* __restrict__ xs,
        float* __restrict__ out) {
    __shared__ int s_adj[NB_ * NB_];
    __shared__ float s_scores[NB_], s_soft[NB_];
    __shared__ int s_perm[P_];
    __shared__ unsigned char s_inperm[NB_], s_sel[NB_], s_allvis[NB_], s_vis[NB_];
    __shared__ int s_starts[NSTART_];
    __shared__ int s_path[MAXLEN_];
    __shared__ unsigned char s_valid[MAXLEN_];
    __shared__ float s_w[MAXLEN_];
    __shared__ int s_cur, s_alive, s_do, s_idx, s_skip;
    __shared__ float s_rv[2];
    __shared__ int s_ri[2];

    const int t = threadIdx.x;

    for (int i = t; i < P_ * H_DIM; i += 128) out[i] = xs[i];
    for (int i = t; i < NB_ * NB_; i += 128) s_adj[i] = adj[i];
    if (t < P_) s_perm[t] = perm[t];
    if (t < NB_) { s_scores[t] = scores[t]; s_allvis[t] = 0; s_sel[t] = 0; }
    __syncthreads();
    if (t < NB_) {
        unsigned char inp = 0;
        for (int j = 0; j < P_; j++) inp |= (s_perm[j] == t) ? 1 : 0;
        s_inperm[t] = inp;
    }
    __syncthreads();

    // softmax(scores)
    float myv = (t < NB_) ? s_scores[t] : -INFINITY;
    float mx = block_max_f(myv, t, s_rv);
    float e = (t < NB_) ? expf(s_scores[t] - mx) : 0.f;
    float ssum = block_sum_f(e, t, s_rv);
    if (t < NB_) s_soft[t] = e / ssum;

    float ninf = block_sum_f((t < NB_ && s_inperm[t]) ? 1.f : 0.f, t, s_rv);
    int nin = (int)(ninf + 0.5f);
    int nok = nin < NSTART_ ? nin : NSTART_;
    __syncthreads();

    // starts = first NSTART of order sorted by (in-perm first, then score desc, stable)
    for (int r = 0; r < NSTART_; r++) {
        bool useIn = (r < nin);
        bool elig = (t < NB_) && !s_sel[t] && (((s_inperm[t] != 0)) == useIn);
        float v = elig ? s_scores[t] : -INFINITY;
        float mv; int mi;
        block_argmax(v, elig ? t : 0x7fffffff, t, s_rv, s_ri, &mv, &mi);
        if (t == 0) s_starts[r] = mi;
        if (t == mi && t < NB_) s_sel[t] = 1;
        __syncthreads();
    }

    for (int s = 0; s < NSTART_; s++) {
        if (t == 0) {
            int start = s_starts[s];
            int ok = (s < nok) ? 1 : 0;
            int skip = (!ok) || s_allvis[start];
            s_skip = skip;
            s_cur = start;
            s_alive = 1;
            s_path[0] = start;
            s_valid[0] = 1;
            int idx = 0, found = 0;
            for (int j = 0; j < P_; j++)
                if (!found && s_perm[j] == start) { idx = j; found = 1; }
            s_idx = idx;
            s_do = (!skip) && found;
        }
        __syncthreads();
        if (t < NB_) s_vis[t] = s_allvis[t];
        __syncthreads();
        if (t == 0) s_vis[s_cur] = 1;
        __syncthreads();

        for (int st = 1; st < MAXLEN_; st++) {
            int cur = s_cur;
            int alive = s_alive;
            bool elig = (t < NB_) && alive && (s_adj[cur * NB_ + t] > 0) && (!s_vis[t]);
            float v = elig ? s_soft[t] : -INFINITY;
            float mv; int mi;
            block_argmax(v, elig ? t : 0x7fffffff, t, s_rv, s_ri, &mv, &mi);
            if (t == 0) {
                int has = (mv > -INFINITY) ? 1 : 0;
                if (has) { s_cur = mi; s_vis[mi] = 1; }
                s_path[st] = has ? mi : cur;
                s_valid[st] = (unsigned char)has;
                s_alive = has;
            }
            __syncthreads();
        }

        if (t == 0) {
            float mxw = -INFINITY;
            for (int st = 0; st < MAXLEN_; st++)
                if (s_valid[st]) mxw = fmaxf(mxw, s_scores[s_path[st]]);
            float sw = 0.f;
            for (int st = 0; st < MAXLEN_; st++) {
                float ev = s_valid[st] ? expf(s_scores[s_path[st]] - mxw) : 0.f;
                s_w[st] = ev; sw += ev;
            }
            float inv = 1.f / sw;
            for (int st = 0; st < MAXLEN_; st++) s_w[st] *= inv;
        }
        __syncthreads();
        if (s_do) {
            float acc = 0.f;
            for (int st = 0; st < MAXLEN_; st++)
                acc += s_w[st] * feats[s_path[st] * H_DIM + t];
            out[s_idx * H_DIM + t] += acc;
        }
        __syncthreads();
        if (!s_skip && t < NB_) s_allvis[t] = s_vis[t];
        __syncthreads();
    }
}

// ---------------- launch ----------------

extern "C" void kernel_launch(void* const* d_in, const int* in_sizes, int n_in,
                              void* d_out, int out_size, void* d_ws, size_t ws_size,
                              hipStream_t stream) {
    const float* v    = (const float*)d_in[0];
    const int*   erow = (const int*)d_in[1];
    const int*   ecol = (const int*)d_in[2];
    const float* W1   = (const float*)d_in[3];
    const float* b1   = (const float*)d_in[4];
    const float* g1   = (const float*)d_in[5];
    const float* be1  = (const float*)d_in[6];
    const float* W2   = (const float*)d_in[7];
    const float* b2   = (const float*)d_in[8];
    const float* g2   = (const float*)d_in[9];
    const float* be2  = (const float*)d_in[10];
    const float* epsp = (const float*)d_in[11];
    const int*   adj  = (const int*)d_in[12];
    const float* scr  = (const float*)d_in[13];
    const float* fts  = (const float*)d_in[14];
    const int*   perm = (const int*)d_in[15];
    const float* xs   = (const float*)d_in[16];

    float* out = (float*)d_out;
    float* wsf = (float*)d_ws;
    float* sums1 = wsf,        *sumsq1 = wsf + 128, *mean1 = wsf + 256, *scl1 = wsf + 384;
    float* sums2 = wsf + 512,  *sumsq2 = wsf + 640, *mean2 = wsf + 768, *scl2 = wsf + 896;

    const int E  = in_sizes[1];
    const int n4 = NH / 4;

    k_zero_stats<<<1, 256, 0, stream>>>(wsf);
    k_init<<<2048, 256, 0, stream>>>((const float4*)v, epsp, (float4*)out, n4);
    k_scatter<<<4096, 256, 0, stream>>>(v, erow, ecol, out, E);
    k_gemm<<<N_NODES / 128, 256, 0, stream>>>(out, out, W1, b1, mean1, scl1, be1,
                                              sums1, sumsq1, 0);
    k_finalize<<<1, 128, 0, stream>>>(sums1, sumsq1, mean1, scl1, g1, 1.f / N_NODES);
    k_gemm<<<N_NODES / 128, 256, 0, stream>>>(out, out, W2, b2, mean1, scl1, be1,
                                              sums2, sumsq2, 1);
    k_finalize<<<1, 128, 0, stream>>>(sums2, sumsq2, mean2, scl2, g2, 1.f / N_NODES);
    k_bnrelu<<<2048, 256, 0, stream>>>((float4*)out, mean2, scl2, be2, n4);
    k_walk<<<1, 128, 0, stream>>>(adj, scr, fts, perm, xs, out + NH);
}

// Round 2
// 984.216 us; speedup vs baseline: 1.6031x; 1.6031x over previous
//
#include <hip/hip_runtime.h>
#include <hip/hip_bf16.h>
#include <math.h>

#define N_NODES 227328
#define H_DIM 128
#define NB_ 111
#define P_ 40
#define MAXLEN_ 10
#define NSTART_ 5
#define NH (N_NODES * H_DIM)
#define SCAN_BLK 1024  // elements per scan block (256 thr x 4)

// ---------------- small utility kernels ----------------

__global__ __launch_bounds__(256) void k_zero_stats(float* wsf) {
    int t = threadIdx.x;
    for (int i = t; i < 1024; i += 256) wsf[i] = 0.f;
}

__global__ __launch_bounds__(256) void k_zero_ints(int* p, int n) {
    int stride = gridDim.x * blockDim.x;
    for (int i = blockIdx.x * blockDim.x + threadIdx.x; i < n; i += stride) p[i] = 0;
}

// ---------------- CSR build ----------------

__global__ __launch_bounds__(256) void k_hist(const int* __restrict__ erow, int* cnt, int E) {
    int stride = gridDim.x * blockDim.x;
    for (int e = blockIdx.x * blockDim.x + threadIdx.x; e < E; e += stride)
        atomicAdd(&cnt[erow[e]], 1);
}

// exclusive scan within blocks of SCAN_BLK elements; block totals to bsum
__global__ __launch_bounds__(256) void k_scan1(const int* __restrict__ cnt, int* __restrict__ ptr,
                                               int* __restrict__ bsum, int n) {
    __shared__ int s_warp[4];
    int t = threadIdx.x;
    int base = blockIdx.x * SCAN_BLK + t * 4;
    int x0 = (base + 0 < n) ? cnt[base + 0] : 0;
    int x1 = (base + 1 < n) ? cnt[base + 1] : 0;
    int x2 = (base + 2 < n) ? cnt[base + 2] : 0;
    int x3 = (base + 3 < n) ? cnt[base + 3] : 0;
    int tsum = x0 + x1 + x2 + x3;
    int lane = t & 63, w = t >> 6;
    int v = tsum;
#pragma unroll
    for (int m = 1; m < 64; m <<= 1) {
        int o = __shfl_up(v, m, 64);
        if (lane >= m) v += o;
    }
    if (lane == 63) s_warp[w] = v;
    __syncthreads();
    int wadd = 0;
    for (int j = 0; j < w; j++) wadd += s_warp[j];
    int excl = v - tsum + wadd;
    if (base + 0 < n) ptr[base + 0] = excl;
    if (base + 1 < n) ptr[base + 1] = excl + x0;
    if (base + 2 < n) ptr[base + 2] = excl + x0 + x1;
    if (base + 3 < n) ptr[base + 3] = excl + x0 + x1 + x2;
    if (t == 0) bsum[blockIdx.x] = s_warp[0] + s_warp[1] + s_warp[2] + s_warp[3];
}

__global__ __launch_bounds__(256) void k_scan2(int* bsum, int nb) {
    __shared__ int s[256];
    int t = threadIdx.x;
    s[t] = (t < nb) ? bsum[t] : 0;
    __syncthreads();
    if (t == 0) {
        int acc = 0;
        for (int i = 0; i < nb; i++) { int x = s[i]; s[i] = acc; acc += x; }
    }
    __syncthreads();
    if (t < nb) bsum[t] = s[t];
}

__global__ __launch_bounds__(256) void k_scan3(int* __restrict__ ptr, const int* __restrict__ bsum,
                                               int* __restrict__ cur, int n, int E) {
    int stride = gridDim.x * blockDim.x;
    for (int i = blockIdx.x * blockDim.x + threadIdx.x; i < n; i += stride) {
        int p = ptr[i] + bsum[i / SCAN_BLK];
        ptr[i] = p;
        cur[i] = p;
    }
    if (blockIdx.x == 0 && threadIdx.x == 0) ptr[n] = E;
}

__global__ __launch_bounds__(256) void k_fill(const int* __restrict__ erow,
                                              const int* __restrict__ ecol,
                                              int* cur, int* __restrict__ col, int E) {
    int stride = gridDim.x * blockDim.x;
    for (int e = blockIdx.x * blockDim.x + threadIdx.x; e < E; e += stride) {
        int p = atomicAdd(&cur[erow[e]], 1);
        col[p] = ecol[e];
    }
}

// one wave per node: agg[r] = eps*v[r] + sum_{e in row r} v[col[e]]
__global__ __launch_bounds__(256) void k_agg(const float* __restrict__ v,
                                             const int* __restrict__ ptr,
                                             const int* __restrict__ col,
                                             const float* __restrict__ epsp,
                                             float* __restrict__ out, int n) {
    int r = (blockIdx.x * 256 + threadIdx.x) >> 6;
    int lane = threadIdx.x & 63;
    if (r >= n) return;
    float eps = epsp[0];
    float2 a = *((const float2*)(v + (size_t)r * H_DIM) + lane);
    float2 acc = make_float2(eps * a.x, eps * a.y);
    int s = ptr[r], e = ptr[r + 1];
    for (int i = s; i < e; i++) {
        int c = col[i];
        float2 b = *((const float2*)(v + (size_t)c * H_DIM) + lane);
        acc.x += b.x;
        acc.y += b.y;
    }
    *((float2*)(out + (size_t)r * H_DIM) + lane) = acc;
}

// ---------------- fallback atomic path ----------------

__global__ __launch_bounds__(256) void k_init(const float4* __restrict__ v4,
                                              const float* __restrict__ epsp,
                                              float4* __restrict__ out4, int n4) {
    float eps = epsp[0];
    int stride = gridDim.x * blockDim.x;
    for (int i = blockIdx.x * blockDim.x + threadIdx.x; i < n4; i += stride) {
        float4 a = v4[i];
        out4[i] = make_float4(eps * a.x, eps * a.y, eps * a.z, eps * a.w);
    }
}

__global__ __launch_bounds__(256) void k_scatter(const float* __restrict__ v,
                                                 const int* __restrict__ erow,
                                                 const int* __restrict__ ecol,
                                                 float* agg, int E) {
    int tid = blockIdx.x * blockDim.x + threadIdx.x;
    int lane = tid & 63;
    int wave = tid >> 6;
    int nwaves = (gridDim.x * blockDim.x) >> 6;
    for (int e = wave; e < E; e += nwaves) {
        int r = erow[e], c = ecol[e];
        const float2 val = *((const float2*)(v + (size_t)c * H_DIM) + lane);
        float* dst = agg + (size_t)r * H_DIM + lane * 2;
        unsafeAtomicAdd(dst, val.x);
        unsafeAtomicAdd(dst + 1, val.y);
    }
}

// ---------------- GEMM (in-place safe): C = [bn_relu?](A) @ W + bias ----------------
__global__ __launch_bounds__(256) void k_gemm(const float* A, float* C,
        const float* __restrict__ W, const float* __restrict__ bias,
        const float* __restrict__ mean, const float* __restrict__ scl,
        const float* __restrict__ beta,
        float* __restrict__ sums, float* __restrict__ sumsq, int applyBN) {
    __shared__ float A_s[128 * 132];
    __shared__ float W_s[128 * 132];
    const int t = threadIdx.x;
    const int tx = t & 15;
    const int ty = t >> 4;
    const size_t row0 = (size_t)blockIdx.x * 128;

    for (int i = t * 4; i < 128 * 128; i += 1024) {
        float4 w4 = *(const float4*)(W + i);
        int k = i >> 7, c = i & 127;
        *(float4*)(W_s + k * 132 + c) = w4;
    }
    for (int i = t * 4; i < 128 * 128; i += 1024) {
        float4 a4 = *(const float4*)(A + row0 * 128 + i);
        int r = i >> 7, c = i & 127;
        if (applyBN) {
            a4.x = fmaxf(fmaf(a4.x - mean[c + 0], scl[c + 0], beta[c + 0]), 0.f);
            a4.y = fmaxf(fmaf(a4.y - mean[c + 1], scl[c + 1], beta[c + 1]), 0.f);
            a4.z = fmaxf(fmaf(a4.z - mean[c + 2], scl[c + 2], beta[c + 2]), 0.f);
            a4.w = fmaxf(fmaf(a4.w - mean[c + 3], scl[c + 3], beta[c + 3]), 0.f);
        }
        *(float4*)(A_s + r * 132 + c) = a4;
    }
    __syncthreads();

    float acc[8][8];
#pragma unroll
    for (int ri = 0; ri < 8; ri++)
#pragma unroll
        for (int ci = 0; ci < 8; ci++) acc[ri][ci] = 0.f;

#pragma unroll 4
    for (int k = 0; k < 128; k++) {
        float a[8], w[8];
#pragma unroll
        for (int ri = 0; ri < 8; ri++) a[ri] = A_s[(ty + 16 * ri) * 132 + k];
#pragma unroll
        for (int ci = 0; ci < 8; ci++) w[ci] = W_s[k * 132 + tx + 16 * ci];
#pragma unroll
        for (int ri = 0; ri < 8; ri++)
#pragma unroll
            for (int ci = 0; ci < 8; ci++)
                acc[ri][ci] = fmaf(a[ri], w[ci], acc[ri][ci]);
    }

    float s[8], s2[8];
#pragma unroll
    for (int ci = 0; ci < 8; ci++) { s[ci] = 0.f; s2[ci] = 0.f; }
#pragma unroll
    for (int ci = 0; ci < 8; ci++) {
        int c = tx + 16 * ci;
        float b = bias[c];
#pragma unroll
        for (int ri = 0; ri < 8; ri++) {
            int r = ty + 16 * ri;
            float val = acc[ri][ci] + b;
            C[(row0 + r) * H_DIM + c] = val;
            s[ci] += val;
            s2[ci] += val * val;
        }
    }
    __syncthreads();
    float* red = A_s;
#pragma unroll
    for (int ci = 0; ci < 8; ci++) {
        int c = tx + 16 * ci;
        red[(c * 16 + ty) * 2 + 0] = s[ci];
        red[(c * 16 + ty) * 2 + 1] = s2[ci];
    }
    __syncthreads();
    if (t < 128) {
        float S = 0.f, S2 = 0.f;
#pragma unroll
        for (int j = 0; j < 16; j++) {
            S += red[(t * 16 + j) * 2];
            S2 += red[(t * 16 + j) * 2 + 1];
        }
        unsafeAtomicAdd(sums + t, S);
        unsafeAtomicAdd(sumsq + t, S2);
    }
}

__global__ void k_finalize(const float* __restrict__ sums, const float* __restrict__ sumsq,
                           float* __restrict__ mean, float* __restrict__ scl,
                           const float* __restrict__ g, float invN) {
    int t = threadIdx.x;
    if (t < H_DIM) {
        float m = sums[t] * invN;
        float var = sumsq[t] * invN - m * m;
        mean[t] = m;
        scl[t] = g[t] * rsqrtf(var + 1e-5f);
    }
}

__global__ __launch_bounds__(256) void k_bnrelu(float4* y4, const float* __restrict__ mean,
                                                const float* __restrict__ scl,
                                                const float* __restrict__ beta, int n4) {
    int stride = gridDim.x * blockDim.x;
    for (int i = blockIdx.x * blockDim.x + threadIdx.x; i < n4; i += stride) {
        int c = (i & 31) * 4;
        float4 a = y4[i];
        a.x = fmaxf(fmaf(a.x - mean[c + 0], scl[c + 0], beta[c + 0]), 0.f);
        a.y = fmaxf(fmaf(a.y - mean[c + 1], scl[c + 1], beta[c + 1]), 0.f);
        a.z = fmaxf(fmaf(a.z - mean[c + 2], scl[c + 2], beta[c + 2]), 0.f);
        a.w = fmaxf(fmaf(a.w - mean[c + 3], scl[c + 3], beta[c + 3]), 0.f);
        y4[i] = a;
    }
}

// ---------------- random walk (tiny, one block) ----------------

__device__ inline float block_max_f(float v, int t, float* s_r) {
#pragma unroll
    for (int m = 1; m < 64; m <<= 1) v = fmaxf(v, __shfl_xor(v, m, 64));
    if ((t & 63) == 0) s_r[t >> 6] = v;
    __syncthreads();
    float r = fmaxf(s_r[0], s_r[1]);
    __syncthreads();
    return r;
}

__device__ inline float block_sum_f(float v, int t, float* s_r) {
#pragma unroll
    for (int m = 1; m < 64; m <<= 1) v += __shfl_xor(v, m, 64);
    if ((t & 63) == 0) s_r[t >> 6] = v;
    __syncthreads();
    float r = s_r[0] + s_r[1];
    __syncthreads();
    return r;
}

__device__ inline void block_argmax(float v, int idx, int t, float* s_rv, int* s_ri,
                                    float* outv, int* outi) {
#pragma unroll
    for (int m = 1; m < 64; m <<= 1) {
        float ov = __shfl_xor(v, m, 64);
        int oi = __shfl_xor(idx, m, 64);
        if (ov > v || (ov == v && oi < idx)) { v = ov; idx = oi; }
    }
    if ((t & 63) == 0) { s_rv[t >> 6] = v; s_ri[t >> 6] = idx; }
    __syncthreads();
    float v0 = s_rv[0], v1 = s_rv[1];
    int i0 = s_ri[0], i1 = s_ri[1];
    if (v1 > v0 || (v1 == v0 && i1 < i0)) { *outv = v1; *outi = i1; }
    else { *outv = v0; *outi = i0; }
    __syncthreads();
}

__global__ __launch_bounds__(128) void k_walk(const int* __restrict__ adj,
        const float* __restrict__ scores, const float* __restrict__ feats,
        const int* __restrict__ perm, const float* __restrict__ xs,
        float* __restrict__ out) {
    __shared__ int s_adj[NB_ * NB_];
    __shared__ float s_scores[NB_], s_soft[NB_];
    __shared__ int s_perm[P_];
    __shared__ unsigned char s_inperm[NB_], s_sel[NB_], s_allvis[NB_], s_vis[NB_];
    __shared__ int s_starts[NSTART_];
    __shared__ int s_path[MAXLEN_];
    __shared__ unsigned char s_valid[MAXLEN_];
    __shared__ float s_w[MAXLEN_];
    __shared__ int s_cur, s_alive, s_do, s_idx, s_skip;
    __shared__ float s_rv[2];
    __shared__ int s_ri[2];

    const int t = threadIdx.x;

    for (int i = t; i < P_ * H_DIM; i += 128) out[i] = xs[i];
    for (int i = t; i < NB_ * NB_; i += 128) s_adj[i] = adj[i];
    if (t < P_) s_perm[t] = perm[t];
    if (t < NB_) { s_scores[t] = scores[t]; s_allvis[t] = 0; s_sel[t] = 0; }
    __syncthreads();
    if (t < NB_) {
        unsigned char inp = 0;
        for (int j = 0; j < P_; j++) inp |= (s_perm[j] == t) ? 1 : 0;
        s_inperm[t] = inp;
    }
    __syncthreads();

    float myv = (t < NB_) ? s_scores[t] : -INFINITY;
    float mx = block_max_f(myv, t, s_rv);
    float e = (t < NB_) ? expf(s_scores[t] - mx) : 0.f;
    float ssum = block_sum_f(e, t, s_rv);
    if (t < NB_) s_soft[t] = e / ssum;

    float ninf = block_sum_f((t < NB_ && s_inperm[t]) ? 1.f : 0.f, t, s_rv);
    int nin = (int)(ninf + 0.5f);
    int nok = nin < NSTART_ ? nin : NSTART_;
    __syncthreads();

    for (int r = 0; r < NSTART_; r++) {
        bool useIn = (r < nin);
        bool elig = (t < NB_) && !s_sel[t] && (((s_inperm[t] != 0)) == useIn);
        float v = elig ? s_scores[t] : -INFINITY;
        float mv; int mi;
        block_argmax(v, elig ? t : 0x7fffffff, t, s_rv, s_ri, &mv, &mi);
        if (t == 0) s_starts[r] = mi;
        if (t == mi && t < NB_) s_sel[t] = 1;
        __syncthreads();
    }

    for (int s = 0; s < NSTART_; s++) {
        if (t == 0) {
            int start = s_starts[s];
            int ok = (s < nok) ? 1 : 0;
            int skip = (!ok) || s_allvis[start];
            s_skip = skip;
            s_cur = start;
            s_alive = 1;
            s_path[0] = start;
            s_valid[0] = 1;
            int idx = 0, found = 0;
            for (int j = 0; j < P_; j++)
                if (!found && s_perm[j] == start) { idx = j; found = 1; }
            s_idx = idx;
            s_do = (!skip) && found;
        }
        __syncthreads();
        if (t < NB_) s_vis[t] = s_allvis[t];
        __syncthreads();
        if (t == 0) s_vis[s_cur] = 1;
        __syncthreads();

        for (int st = 1; st < MAXLEN_; st++) {
            int cur = s_cur;
            int alive = s_alive;
            bool elig = (t < NB_) && alive && (s_adj[cur * NB_ + t] > 0) && (!s_vis[t]);
            float v = elig ? s_soft[t] : -INFINITY;
            float mv; int mi;
            block_argmax(v, elig ? t : 0x7fffffff, t, s_rv, s_ri, &mv, &mi);
            if (t == 0) {
                int has = (mv > -INFINITY) ? 1 : 0;
                if (has) { s_cur = mi; s_vis[mi] = 1; }
                s_path[st] = has ? mi : cur;
                s_valid[st] = (unsigned char)has;
                s_alive = has;
            }
            __syncthreads();
        }

        if (t == 0) {
            float mxw = -INFINITY;
            for (int st = 0; st < MAXLEN_; st++)
                if (s_valid[st]) mxw = fmaxf(mxw, s_scores[s_path[st]]);
            float sw = 0.f;
            for (int st = 0; st < MAXLEN_; st++) {
                float ev = s_valid[st] ? expf(s_scores[s_path[st]] - mxw) : 0.f;
                s_w[st] = ev; sw += ev;
            }
            float inv = 1.f / sw;
            for (int st = 0; st < MAXLEN_; st++) s_w[st] *= inv;
        }
        __syncthreads();
        if (s_do) {
            float acc = 0.f;
            for (int st = 0; st < MAXLEN_; st++)
                acc += s_w[st] * feats[s_path[st] * H_DIM + t];
            out[s_idx * H_DIM + t] += acc;
        }
        __syncthreads();
        if (!s_skip && t < NB_) s_allvis[t] = s_vis[t];
        __syncthreads();
    }
}

// ---------------- launch ----------------

extern "C" void kernel_launch(void* const* d_in, const int* in_sizes, int n_in,
                              void* d_out, int out_size, void* d_ws, size_t ws_size,
                              hipStream_t stream) {
    const float* v    = (const float*)d_in[0];
    const int*   erow = (const int*)d_in[1];
    const int*   ecol = (const int*)d_in[2];
    const float* W1   = (const float*)d_in[3];
    const float* b1   = (const float*)d_in[4];
    const float* g1   = (const float*)d_in[5];
    const float* be1  = (const float*)d_in[6];
    const float* W2   = (const float*)d_in[7];
    const float* b2   = (const float*)d_in[8];
    const float* g2   = (const float*)d_in[9];
    const float* be2  = (const float*)d_in[10];
    const float* epsp = (const float*)d_in[11];
    const int*   adj  = (const int*)d_in[12];
    const float* scr  = (const float*)d_in[13];
    const float* fts  = (const float*)d_in[14];
    const int*   perm = (const int*)d_in[15];
    const float* xs   = (const float*)d_in[16];

    float* out = (float*)d_out;
    float* wsf = (float*)d_ws;
    float* sums1 = wsf,        *sumsq1 = wsf + 128, *mean1 = wsf + 256, *scl1 = wsf + 384;
    float* sums2 = wsf + 512,  *sumsq2 = wsf + 640, *mean2 = wsf + 768, *scl2 = wsf + 896;

    const int E  = in_sizes[1];
    const int N  = N_NODES;
    const int n4 = NH / 4;

    // CSR scratch layout (after the 1024-float stats block)
    int* ws_i = (int*)(wsf + 1024);
    int* cnt  = ws_i;                   // N+1
    int* ptr  = ws_i + (N + 1);         // N+1
    int* cur  = ws_i + 2 * (N + 1);     // N
    int* col  = ws_i + 3 * (N + 1);     // E
    size_t need = 1024 * 4 + (size_t)(3 * (N + 1) + E) * 4;

    k_zero_stats<<<1, 256, 0, stream>>>(wsf);

    if (ws_size >= need) {
        const int nb = (N + SCAN_BLK - 1) / SCAN_BLK;   // 222
        int* bsum = cnt;  // reuse cnt region for block sums after scan1 reads it
        k_zero_ints<<<512, 256, 0, stream>>>(cnt, N + 1);
        k_hist<<<1024, 256, 0, stream>>>(erow, cnt, E);
        k_scan1<<<nb, 256, 0, stream>>>(cnt, ptr, cur /*tmp bsum*/, N);
        k_scan2<<<1, 256, 0, stream>>>(cur, nb);
        k_scan3<<<512, 256, 0, stream>>>(ptr, cur, cnt /*cur array*/, N, E);
        // note: after scan3, "cnt" holds the running fill cursors
        k_fill<<<1024, 256, 0, stream>>>(erow, ecol, cnt, col, E);
        k_agg<<<N / 4, 256, 0, stream>>>(v, ptr, col, epsp, out, N);
    } else {
        k_init<<<2048, 256, 0, stream>>>((const float4*)v, epsp, (float4*)out, n4);
        k_scatter<<<4096, 256, 0, stream>>>(v, erow, ecol, out, E);
    }

    k_gemm<<<N / 128, 256, 0, stream>>>(out, out, W1, b1, mean1, scl1, be1,
                                        sums1, sumsq1, 0);
    k_finalize<<<1, 128, 0, stream>>>(sums1, sumsq1, mean1, scl1, g1, 1.f / N);
    k_gemm<<<N / 128, 256, 0, stream>>>(out, out, W2, b2, mean1, scl1, be1,
                                        sums2, sumsq2, 1);
    k_finalize<<<1, 128, 0, stream>>>(sums2, sumsq2, mean2, scl2, g2, 1.f / N);
    k_bnrelu<<<2048, 256, 0, stream>>>((float4*)out, mean2, scl2, be2, n4);
    k_walk<<<1, 128, 0, stream>>>(adj, scr, fts, perm, xs, out + NH);
}

// Round 3
// 710.519 us; speedup vs baseline: 2.2207x; 1.3852x over previous
//
#include <hip/hip_runtime.h>
#include <hip/hip_bf16.h>
#include <math.h>

#define N_NODES 227328
#define H_DIM 128
#define NB_ 111
#define P_ 40
#define MAXLEN_ 10
#define NSTART_ 5
#define NH (N_NODES * H_DIM)
#define SCAN_BLK 1024  // elements per scan block (256 thr x 4)

typedef __attribute__((ext_vector_type(8))) short short8;
typedef __attribute__((ext_vector_type(4))) float f32x4;

// ---------------- small utility kernels ----------------

__global__ __launch_bounds__(256) void k_zero_stats(float* wsf) {
    int t = threadIdx.x;
    for (int i = t; i < 1280; i += 256) wsf[i] = 0.f;
}

__global__ __launch_bounds__(256) void k_zero_ints(int* p, int n) {
    int stride = gridDim.x * blockDim.x;
    for (int i = blockIdx.x * blockDim.x + threadIdx.x; i < n; i += stride) p[i] = 0;
}

// ---------------- CSR build ----------------

__global__ __launch_bounds__(256) void k_hist(const int* __restrict__ erow, int* cnt, int E) {
    int stride = gridDim.x * blockDim.x;
    for (int e = blockIdx.x * blockDim.x + threadIdx.x; e < E; e += stride)
        atomicAdd(&cnt[erow[e]], 1);
}

__global__ __launch_bounds__(256) void k_scan1(const int* __restrict__ cnt, int* __restrict__ ptr,
                                               int* __restrict__ bsum, int n) {
    __shared__ int s_warp[4];
    int t = threadIdx.x;
    int base = blockIdx.x * SCAN_BLK + t * 4;
    int x0 = (base + 0 < n) ? cnt[base + 0] : 0;
    int x1 = (base + 1 < n) ? cnt[base + 1] : 0;
    int x2 = (base + 2 < n) ? cnt[base + 2] : 0;
    int x3 = (base + 3 < n) ? cnt[base + 3] : 0;
    int tsum = x0 + x1 + x2 + x3;
    int lane = t & 63, w = t >> 6;
    int v = tsum;
#pragma unroll
    for (int m = 1; m < 64; m <<= 1) {
        int o = __shfl_up(v, m, 64);
        if (lane >= m) v += o;
    }
    if (lane == 63) s_warp[w] = v;
    __syncthreads();
    int wadd = 0;
    for (int j = 0; j < w; j++) wadd += s_warp[j];
    int excl = v - tsum + wadd;
    if (base + 0 < n) ptr[base + 0] = excl;
    if (base + 1 < n) ptr[base + 1] = excl + x0;
    if (base + 2 < n) ptr[base + 2] = excl + x0 + x1;
    if (base + 3 < n) ptr[base + 3] = excl + x0 + x1 + x2;
    if (t == 0) bsum[blockIdx.x] = s_warp[0] + s_warp[1] + s_warp[2] + s_warp[3];
}

__global__ __launch_bounds__(256) void k_scan2(int* bsum, int nb) {
    __shared__ int s[256];
    int t = threadIdx.x;
    s[t] = (t < nb) ? bsum[t] : 0;
    __syncthreads();
    if (t == 0) {
        int acc = 0;
        for (int i = 0; i < nb; i++) { int x = s[i]; s[i] = acc; acc += x; }
    }
    __syncthreads();
    if (t < nb) bsum[t] = s[t];
}

__global__ __launch_bounds__(256) void k_scan3(int* __restrict__ ptr, const int* __restrict__ bsum,
                                               int* __restrict__ cur, int n, int E) {
    int stride = gridDim.x * blockDim.x;
    for (int i = blockIdx.x * blockDim.x + threadIdx.x; i < n; i += stride) {
        int p = ptr[i] + bsum[i / SCAN_BLK];
        ptr[i] = p;
        cur[i] = p;
    }
    if (blockIdx.x == 0 && threadIdx.x == 0) ptr[n] = E;
}

__global__ __launch_bounds__(256) void k_fill(const int* __restrict__ erow,
                                              const int* __restrict__ ecol,
                                              int* cur, int* __restrict__ col, int E) {
    int stride = gridDim.x * blockDim.x;
    for (int e = blockIdx.x * blockDim.x + threadIdx.x; e < E; e += stride) {
        int p = atomicAdd(&cur[erow[e]], 1);
        col[p] = ecol[e];
    }
}

// one wave per node: agg[r] = eps*v[r] + sum_{e in row r} v[col[e]]
__global__ __launch_bounds__(256) void k_agg(const float* __restrict__ v,
                                             const int* __restrict__ ptr,
                                             const int* __restrict__ col,
                                             const float* __restrict__ epsp,
                                             float* __restrict__ out, int n) {
    int r = (blockIdx.x * 256 + threadIdx.x) >> 6;
    int lane = threadIdx.x & 63;
    if (r >= n) return;
    float eps = epsp[0];
    float2 a = *((const float2*)(v + (size_t)r * H_DIM) + lane);
    float2 acc = make_float2(eps * a.x, eps * a.y);
    int s = ptr[r], e = ptr[r + 1];
    for (int i = s; i < e; i++) {
        int c = col[i];
        float2 b = *((const float2*)(v + (size_t)c * H_DIM) + lane);
        acc.x += b.x;
        acc.y += b.y;
    }
    *((float2*)(out + (size_t)r * H_DIM) + lane) = acc;
}

// ---------------- fallback atomic path ----------------

__global__ __launch_bounds__(256) void k_init(const float4* __restrict__ v4,
                                              const float* __restrict__ epsp,
                                              float4* __restrict__ out4, int n4) {
    float eps = epsp[0];
    int stride = gridDim.x * blockDim.x;
    for (int i = blockIdx.x * blockDim.x + threadIdx.x; i < n4; i += stride) {
        float4 a = v4[i];
        out4[i] = make_float4(eps * a.x, eps * a.y, eps * a.z, eps * a.w);
    }
}

__global__ __launch_bounds__(256) void k_scatter(const float* __restrict__ v,
                                                 const int* __restrict__ erow,
                                                 const int* __restrict__ ecol,
                                                 float* agg, int E) {
    int tid = blockIdx.x * blockDim.x + threadIdx.x;
    int lane = tid & 63;
    int wave = tid >> 6;
    int nwaves = (gridDim.x * blockDim.x) >> 6;
    for (int e = wave; e < E; e += nwaves) {
        int r = erow[e], c = ecol[e];
        const float2 val = *((const float2*)(v + (size_t)c * H_DIM) + lane);
        float* dst = agg + (size_t)r * H_DIM + lane * 2;
        unsafeAtomicAdd(dst, val.x);
        unsafeAtomicAdd(dst + 1, val.y);
    }
}

// ---------------- MFMA GEMM: C = [bnrelu?](A) @ W + bias, fp32 via bf16 hi/lo split ----
// 128x128 tile per block, 4 waves x (32 rows x 128 cols), mfma_f32_16x16x32_bf16.
// A fragments load straight from global; W^T hi/lo staged in LDS (stride 136).
// Error of dropped lo*lo term ~2^-16 relative -> effectively fp32.

__device__ inline void split8(const float* xs, short8& hi, short8& lo) {
#pragma unroll
    for (int e = 0; e < 8; e++) {
        unsigned u = __float_as_uint(xs[e]);
        hi[e] = (short)(unsigned short)(u >> 16);
        float hf = __uint_as_float(u & 0xFFFF0000u);
        lo[e] = (short)(unsigned short)(__float_as_uint(xs[e] - hf) >> 16);
    }
}

template <int BN>
__global__ __launch_bounds__(256, 2) void k_gemm_mfma(
        const float* __restrict__ A, float* __restrict__ C,
        const float* __restrict__ W, const float* __restrict__ bias,
        const float* __restrict__ scl_in, const float* __restrict__ of_in,
        float* __restrict__ sums, float* __restrict__ sumsq) {
    __shared__ unsigned short Whi[128 * 136];   // 34816 B
    __shared__ unsigned short Wlo[128 * 136];   // 34816 B
    __shared__ float scof[256];                 // sc[128], of[128]
    __shared__ float stats[2][4][128];          // 4096 B

    const int t = threadIdx.x;
    const int w = t >> 6;
    const int l = t & 63;
    const int n = l & 15;       // A row-in-frag / B(=W) col-in-frag
    const int g = l >> 4;       // k-octet group
    const size_t row0 = (size_t)blockIdx.x * 128 + w * 32;

    // ---- stage W^T hi/lo (coalesced global reads, scalar LDS writes) ----
#pragma unroll 8
    for (int it = 0; it < 64; ++it) {
        int k = it * 2 + (t >> 7);
        int nn = t & 127;
        float wv = W[k * 128 + nn];
        unsigned u = __float_as_uint(wv);
        Whi[nn * 136 + k] = (unsigned short)(u >> 16);
        float hf = __uint_as_float(u & 0xFFFF0000u);
        Wlo[nn * 136 + k] = (unsigned short)(__float_as_uint(wv - hf) >> 16);
    }
    if (BN && t < 128) { scof[t] = scl_in[t]; scof[128 + t] = of_in[t]; }
    __syncthreads();

    float breg[8];
#pragma unroll
    for (int cb = 0; cb < 8; cb++) breg[cb] = bias[cb * 16 + n];

    f32x4 acc[2][8];
#pragma unroll
    for (int rf = 0; rf < 2; rf++)
#pragma unroll
        for (int cb = 0; cb < 8; cb++) acc[rf][cb] = (f32x4){0.f, 0.f, 0.f, 0.f};

    const float* Arow0 = A + (row0 + n) * H_DIM;
    const float* Arow1 = A + (row0 + 16 + n) * H_DIM;

#pragma unroll
    for (int kb = 0; kb < 4; kb++) {
        const int k0 = kb * 32 + g * 8;
        float4 x00 = *(const float4*)(Arow0 + k0);
        float4 x01 = *(const float4*)(Arow0 + k0 + 4);
        float4 x10 = *(const float4*)(Arow1 + k0);
        float4 x11 = *(const float4*)(Arow1 + k0 + 4);
        float xs0[8] = {x00.x, x00.y, x00.z, x00.w, x01.x, x01.y, x01.z, x01.w};
        float xs1[8] = {x10.x, x10.y, x10.z, x10.w, x11.x, x11.y, x11.z, x11.w};
        if (BN) {
            float sc[8], of[8];
            float4 sa = *(const float4*)(scof + k0);
            float4 sb = *(const float4*)(scof + k0 + 4);
            float4 oa = *(const float4*)(scof + 128 + k0);
            float4 ob = *(const float4*)(scof + 128 + k0 + 4);
            sc[0] = sa.x; sc[1] = sa.y; sc[2] = sa.z; sc[3] = sa.w;
            sc[4] = sb.x; sc[5] = sb.y; sc[6] = sb.z; sc[7] = sb.w;
            of[0] = oa.x; of[1] = oa.y; of[2] = oa.z; of[3] = oa.w;
            of[4] = ob.x; of[5] = ob.y; of[6] = ob.z; of[7] = ob.w;
#pragma unroll
            for (int e = 0; e < 8; e++) {
                xs0[e] = fmaxf(fmaf(xs0[e], sc[e], of[e]), 0.f);
                xs1[e] = fmaxf(fmaf(xs1[e], sc[e], of[e]), 0.f);
            }
        }
        short8 ah0, al0, ah1, al1;
        split8(xs0, ah0, al0);
        split8(xs1, ah1, al1);

        short8 wh[8], wl[8];
        const int wb = n * 136 + kb * 32 + g * 8;
#pragma unroll
        for (int cb = 0; cb < 8; cb++) {
            wh[cb] = *(const short8*)(Whi + cb * 2176 + wb);
            wl[cb] = *(const short8*)(Wlo + cb * 2176 + wb);
        }
#pragma unroll
        for (int cb = 0; cb < 8; cb++) {
            acc[0][cb] = __builtin_amdgcn_mfma_f32_16x16x32_bf16(ah0, wh[cb], acc[0][cb], 0, 0, 0);
            acc[1][cb] = __builtin_amdgcn_mfma_f32_16x16x32_bf16(ah1, wh[cb], acc[1][cb], 0, 0, 0);
            acc[0][cb] = __builtin_amdgcn_mfma_f32_16x16x32_bf16(al0, wh[cb], acc[0][cb], 0, 0, 0);
            acc[1][cb] = __builtin_amdgcn_mfma_f32_16x16x32_bf16(al1, wh[cb], acc[1][cb], 0, 0, 0);
            acc[0][cb] = __builtin_amdgcn_mfma_f32_16x16x32_bf16(ah0, wl[cb], acc[0][cb], 0, 0, 0);
            acc[1][cb] = __builtin_amdgcn_mfma_f32_16x16x32_bf16(ah1, wl[cb], acc[1][cb], 0, 0, 0);
        }
    }

    // epilogue: bias add, store, per-column stats
    float s[8], s2[8];
#pragma unroll
    for (int cb = 0; cb < 8; cb++) { s[cb] = 0.f; s2[cb] = 0.f; }
#pragma unroll
    for (int cb = 0; cb < 8; cb++) {
        const int c = cb * 16 + n;
#pragma unroll
        for (int rf = 0; rf < 2; rf++) {
            f32x4 o = acc[rf][cb];
            const size_t rbase = (row0 + rf * 16 + g * 4) * H_DIM + c;
#pragma unroll
            for (int r = 0; r < 4; r++) {
                float val = o[r] + breg[cb];
                C[rbase + (size_t)r * H_DIM] = val;
                s[cb] += val;
                s2[cb] += val * val;
            }
        }
    }
#pragma unroll
    for (int cb = 0; cb < 8; cb++) {
        s[cb] += __shfl_xor(s[cb], 16, 64);
        s[cb] += __shfl_xor(s[cb], 32, 64);
        s2[cb] += __shfl_xor(s2[cb], 16, 64);
        s2[cb] += __shfl_xor(s2[cb], 32, 64);
    }
    if (g == 0) {
#pragma unroll
        for (int cb = 0; cb < 8; cb++) {
            stats[0][w][cb * 16 + n] = s[cb];
            stats[1][w][cb * 16 + n] = s2[cb];
        }
    }
    __syncthreads();
    if (t < 128) {
        float S  = stats[0][0][t] + stats[0][1][t] + stats[0][2][t] + stats[0][3][t];
        float S2 = stats[1][0][t] + stats[1][1][t] + stats[1][2][t] + stats[1][3][t];
        unsafeAtomicAdd(sums + t, S);
        unsafeAtomicAdd(sumsq + t, S2);
    }
}

__global__ void k_finalize(const float* __restrict__ sums, const float* __restrict__ sumsq,
                           float* __restrict__ mean, float* __restrict__ scl,
                           float* __restrict__ of,
                           const float* __restrict__ g, const float* __restrict__ beta,
                           float invN) {
    int t = threadIdx.x;
    if (t < H_DIM) {
        float m = sums[t] * invN;
        float var = sumsq[t] * invN - m * m;
        float sc = g[t] * rsqrtf(var + 1e-5f);
        mean[t] = m;
        scl[t] = sc;
        of[t] = beta[t] - m * sc;
    }
}

__global__ __launch_bounds__(256) void k_bnrelu(float4* y4, const float* __restrict__ mean,
                                                const float* __restrict__ scl,
                                                const float* __restrict__ beta, int n4) {
    int stride = gridDim.x * blockDim.x;
    for (int i = blockIdx.x * blockDim.x + threadIdx.x; i < n4; i += stride) {
        int c = (i & 31) * 4;
        float4 a = y4[i];
        a.x = fmaxf(fmaf(a.x - mean[c + 0], scl[c + 0], beta[c + 0]), 0.f);
        a.y = fmaxf(fmaf(a.y - mean[c + 1], scl[c + 1], beta[c + 1]), 0.f);
        a.z = fmaxf(fmaf(a.z - mean[c + 2], scl[c + 2], beta[c + 2]), 0.f);
        a.w = fmaxf(fmaf(a.w - mean[c + 3], scl[c + 3], beta[c + 3]), 0.f);
        y4[i] = a;
    }
}

// ---------------- random walk (tiny, one block) ----------------

__device__ inline float block_max_f(float v, int t, float* s_r) {
#pragma unroll
    for (int m = 1; m < 64; m <<= 1) v = fmaxf(v, __shfl_xor(v, m, 64));
    if ((t & 63) == 0) s_r[t >> 6] = v;
    __syncthreads();
    float r = fmaxf(s_r[0], s_r[1]);
    __syncthreads();
    return r;
}

__device__ inline float block_sum_f(float v, int t, float* s_r) {
#pragma unroll
    for (int m = 1; m < 64; m <<= 1) v += __shfl_xor(v, m, 64);
    if ((t & 63) == 0) s_r[t >> 6] = v;
    __syncthreads();
    float r = s_r[0] + s_r[1];
    __syncthreads();
    return r;
}

__device__ inline void block_argmax(float v, int idx, int t, float* s_rv, int* s_ri,
                                    float* outv, int* outi) {
#pragma unroll
    for (int m = 1; m < 64; m <<= 1) {
        float ov = __shfl_xor(v, m, 64);
        int oi = __shfl_xor(idx, m, 64);
        if (ov > v || (ov == v && oi < idx)) { v = ov; idx = oi; }
    }
    if ((t & 63) == 0) { s_rv[t >> 6] = v; s_ri[t >> 6] = idx; }
    __syncthreads();
    float v0 = s_rv[0], v1 = s_rv[1];
    int i0 = s_ri[0], i1 = s_ri[1];
    if (v1 > v0 || (v1 == v0 && i1 < i0)) { *outv = v1; *outi = i1; }
    else { *outv = v0; *outi = i0; }
    __syncthreads();
}

__global__ __launch_bounds__(128) void k_walk(const int* __restrict__ adj,
        const float* __restrict__ scores, const float* __restrict__ feats,
        const int* __restrict__ perm, const float* __restrict__ xs,
        float* __restrict__ out) {
    __shared__ int s_adj[NB_ * NB_];
    __shared__ float s_scores[NB_], s_soft[NB_];
    __shared__ int s_perm[P_];
    __shared__ unsigned char s_inperm[NB_], s_sel[NB_], s_allvis[NB_], s_vis[NB_];
    __shared__ int s_starts[NSTART_];
    __shared__ int s_path[MAXLEN_];
    __shared__ unsigned char s_valid[MAXLEN_];
    __shared__ float s_w[MAXLEN_];
    __shared__ int s_cur, s_alive, s_do, s_idx, s_skip;
    __shared__ float s_rv[2];
    __shared__ int s_ri[2];

    const int t = threadIdx.x;

    for (int i = t; i < P_ * H_DIM; i += 128) out[i] = xs[i];
    for (int i = t; i < NB_ * NB_; i += 128) s_adj[i] = adj[i];
    if (t < P_) s_perm[t] = perm[t];
    if (t < NB_) { s_scores[t] = scores[t]; s_allvis[t] = 0; s_sel[t] = 0; }
    __syncthreads();
    if (t < NB_) {
        unsigned char inp = 0;
        for (int j = 0; j < P_; j++) inp |= (s_perm[j] == t) ? 1 : 0;
        s_inperm[t] = inp;
    }
    __syncthreads();

    float myv = (t < NB_) ? s_scores[t] : -INFINITY;
    float mx = block_max_f(myv, t, s_rv);
    float e = (t < NB_) ? expf(s_scores[t] - mx) : 0.f;
    float ssum = block_sum_f(e, t, s_rv);
    if (t < NB_) s_soft[t] = e / ssum;

    float ninf = block_sum_f((t < NB_ && s_inperm[t]) ? 1.f : 0.f, t, s_rv);
    int nin = (int)(ninf + 0.5f);
    int nok = nin < NSTART_ ? nin : NSTART_;
    __syncthreads();

    for (int r = 0; r < NSTART_; r++) {
        bool useIn = (r < nin);
        bool elig = (t < NB_) && !s_sel[t] && (((s_inperm[t] != 0)) == useIn);
        float v = elig ? s_scores[t] : -INFINITY;
        float mv; int mi;
        block_argmax(v, elig ? t : 0x7fffffff, t, s_rv, s_ri, &mv, &mi);
        if (t == 0) s_starts[r] = mi;
        if (t == mi && t < NB_) s_sel[t] = 1;
        __syncthreads();
    }

    for (int s = 0; s < NSTART_; s++) {
        if (t == 0) {
            int start = s_starts[s];
            int ok = (s < nok) ? 1 : 0;
            int skip = (!ok) || s_allvis[start];
            s_skip = skip;
            s_cur = start;
            s_alive = 1;
            s_path[0] = start;
            s_valid[0] = 1;
            int idx = 0, found = 0;
            for (int j = 0; j < P_; j++)
                if (!found && s_perm[j] == start) { idx = j; found = 1; }
            s_idx = idx;
            s_do = (!skip) && found;
        }
        __syncthreads();
        if (t < NB_) s_vis[t] = s_allvis[t];
        __syncthreads();
        if (t == 0) s_vis[s_cur] = 1;
        __syncthreads();

        for (int st = 1; st < MAXLEN_; st++) {
            int cur = s_cur;
            int alive = s_alive;
            bool elig = (t < NB_) && alive && (s_adj[cur * NB_ + t] > 0) && (!s_vis[t]);
            float v = elig ? s_soft[t] : -INFINITY;
            float mv; int mi;
            block_argmax(v, elig ? t : 0x7fffffff, t, s_rv, s_ri, &mv, &mi);
            if (t == 0) {
                int has = (mv > -INFINITY) ? 1 : 0;
                if (has) { s_cur = mi; s_vis[mi] = 1; }
                s_path[st] = has ? mi : cur;
                s_valid[st] = (unsigned char)has;
                s_alive = has;
            }
            __syncthreads();
        }

        if (t == 0) {
            float mxw = -INFINITY;
            for (int st = 0; st < MAXLEN_; st++)
                if (s_valid[st]) mxw = fmaxf(mxw, s_scores[s_path[st]]);
            float sw = 0.f;
            for (int st = 0; st < MAXLEN_; st++) {
                float ev = s_valid[st] ? expf(s_scores[s_path[st]] - mxw) : 0.f;
                s_w[st] = ev; sw += ev;
            }
            float inv = 1.f / sw;
            for (int st = 0; st < MAXLEN_; st++) s_w[st] *= inv;
        }
        __syncthreads();
        if (s_do) {
            float acc = 0.f;
            for (int st = 0; st < MAXLEN_; st++)
                acc += s_w[st] * feats[s_path[st] * H_DIM + t];
            out[s_idx * H_DIM + t] += acc;
        }
        __syncthreads();
        if (!s_skip && t < NB_) s_allvis[t] = s_vis[t];
        __syncthreads();
    }
}

// ---------------- launch ----------------

extern "C" void kernel_launch(void* const* d_in, const int* in_sizes, int n_in,
                              void* d_out, int out_size, void* d_ws, size_t ws_size,
                              hipStream_t stream) {
    const float* v    = (const float*)d_in[0];
    const int*   erow = (const int*)d_in[1];
    const int*   ecol = (const int*)d_in[2];
    const float* W1   = (const float*)d_in[3];
    const float* b1   = (const float*)d_in[4];
    const float* g1   = (const float*)d_in[5];
    const float* be1  = (const float*)d_in[6];
    const float* W2   = (const float*)d_in[7];
    const float* b2   = (const float*)d_in[8];
    const float* g2   = (const float*)d_in[9];
    const float* be2  = (const float*)d_in[10];
    const float* epsp = (const float*)d_in[11];
    const int*   adj  = (const int*)d_in[12];
    const float* scr  = (const float*)d_in[13];
    const float* fts  = (const float*)d_in[14];
    const int*   perm = (const int*)d_in[15];
    const float* xs   = (const float*)d_in[16];

    float* out = (float*)d_out;
    float* wsf = (float*)d_ws;
    float* sums1 = wsf,        *sumsq1 = wsf + 128,  *mean1 = wsf + 256,  *scl1 = wsf + 384,  *of1 = wsf + 512;
    float* sums2 = wsf + 640,  *sumsq2 = wsf + 768,  *mean2 = wsf + 896,  *scl2 = wsf + 1024, *of2 = wsf + 1152;

    const int E  = in_sizes[1];
    const int N  = N_NODES;
    const int n4 = NH / 4;

    int* ws_i = (int*)(wsf + 1280);
    int* cnt  = ws_i;                   // N+1
    int* ptr  = ws_i + (N + 1);         // N+1
    int* cur  = ws_i + 2 * (N + 1);     // N
    int* col  = ws_i + 3 * (N + 1);     // E
    size_t need = 1280 * 4 + (size_t)(3 * (N + 1) + E) * 4;

    k_zero_stats<<<1, 256, 0, stream>>>(wsf);

    if (ws_size >= need) {
        const int nb = (N + SCAN_BLK - 1) / SCAN_BLK;   // 222
        k_zero_ints<<<512, 256, 0, stream>>>(cnt, N + 1);
        k_hist<<<1024, 256, 0, stream>>>(erow, cnt, E);
        k_scan1<<<nb, 256, 0, stream>>>(cnt, ptr, cur /*tmp bsum*/, N);
        k_scan2<<<1, 256, 0, stream>>>(cur, nb);
        k_scan3<<<512, 256, 0, stream>>>(ptr, cur, cnt /*becomes fill cursors*/, N, E);
        k_fill<<<1024, 256, 0, stream>>>(erow, ecol, cnt, col, E);
        k_agg<<<N / 4, 256, 0, stream>>>(v, ptr, col, epsp, out, N);
    } else {
        k_init<<<2048, 256, 0, stream>>>((const float4*)v, epsp, (float4*)out, n4);
        k_scatter<<<4096, 256, 0, stream>>>(v, erow, ecol, out, E);
    }

    k_gemm_mfma<0><<<N / 128, 256, 0, stream>>>(out, out, W1, b1, nullptr, nullptr,
                                                sums1, sumsq1);
    k_finalize<<<1, 128, 0, stream>>>(sums1, sumsq1, mean1, scl1, of1, g1, be1, 1.f / N);
    k_gemm_mfma<1><<<N / 128, 256, 0, stream>>>(out, out, W2, b2, scl1, of1,
                                                sums2, sumsq2);
    k_finalize<<<1, 128, 0, stream>>>(sums2, sumsq2, mean2, scl2, of2, g2, be2, 1.f / N);
    k_bnrelu<<<2048, 256, 0, stream>>>((float4*)out, mean2, scl2, be2, n4);
    k_walk<<<1, 128, 0, stream>>>(adj, scr, fts, perm, xs, out + NH);
}

// Round 4
// 655.516 us; speedup vs baseline: 2.4070x; 1.0839x over previous
//
#include <hip/hip_runtime.h>
#include <hip/hip_bf16.h>
#include <math.h>

#define N_NODES 227328
#define H_DIM 128
#define NB_ 111
#define P_ 40
#define MAXLEN_ 10
#define NSTART_ 5
#define NH (N_NODES * H_DIM)
#define SCAN_BLK 1024  // elements per scan block (256 thr x 4)

typedef __attribute__((ext_vector_type(8))) short short8;
typedef __attribute__((ext_vector_type(4))) float f32x4;

// ---------------- zero kernel (stats + counts, one launch) ----------------

__global__ __launch_bounds__(256) void k_zero(float* wsf, int* cnt, int n) {
    int gstride = gridDim.x * blockDim.x;
    for (int i = blockIdx.x * blockDim.x + threadIdx.x; i < n; i += gstride) cnt[i] = 0;
    if (blockIdx.x == 0)
        for (int i = threadIdx.x; i < 1280; i += 256) wsf[i] = 0.f;
}

// ---------------- CSR build ----------------

__global__ __launch_bounds__(256) void k_hist(const int* __restrict__ erow, int* cnt, int E) {
    int stride = gridDim.x * blockDim.x;
    for (int e = blockIdx.x * blockDim.x + threadIdx.x; e < E; e += stride)
        atomicAdd(&cnt[erow[e]], 1);
}

__global__ __launch_bounds__(256) void k_scan1(const int* __restrict__ cnt, int* __restrict__ ptr,
                                               int* __restrict__ bsum, int n) {
    __shared__ int s_warp[4];
    int t = threadIdx.x;
    int base = blockIdx.x * SCAN_BLK + t * 4;
    int x0 = (base + 0 < n) ? cnt[base + 0] : 0;
    int x1 = (base + 1 < n) ? cnt[base + 1] : 0;
    int x2 = (base + 2 < n) ? cnt[base + 2] : 0;
    int x3 = (base + 3 < n) ? cnt[base + 3] : 0;
    int tsum = x0 + x1 + x2 + x3;
    int lane = t & 63, w = t >> 6;
    int v = tsum;
#pragma unroll
    for (int m = 1; m < 64; m <<= 1) {
        int o = __shfl_up(v, m, 64);
        if (lane >= m) v += o;
    }
    if (lane == 63) s_warp[w] = v;
    __syncthreads();
    int wadd = 0;
    for (int j = 0; j < w; j++) wadd += s_warp[j];
    int excl = v - tsum + wadd;
    if (base + 0 < n) ptr[base + 0] = excl;
    if (base + 1 < n) ptr[base + 1] = excl + x0;
    if (base + 2 < n) ptr[base + 2] = excl + x0 + x1;
    if (base + 3 < n) ptr[base + 3] = excl + x0 + x1 + x2;
    if (t == 0) bsum[blockIdx.x] = s_warp[0] + s_warp[1] + s_warp[2] + s_warp[3];
}

__global__ __launch_bounds__(256) void k_scan2(int* bsum, int nb) {
    __shared__ int s[256];
    int t = threadIdx.x;
    s[t] = (t < nb) ? bsum[t] : 0;
    __syncthreads();
    if (t == 0) {
        int acc = 0;
        for (int i = 0; i < nb; i++) { int x = s[i]; s[i] = acc; acc += x; }
    }
    __syncthreads();
    if (t < nb) bsum[t] = s[t];
}

__global__ __launch_bounds__(256) void k_scan3(int* __restrict__ ptr, const int* __restrict__ bsum,
                                               int* __restrict__ cur, int n, int E) {
    int stride = gridDim.x * blockDim.x;
    for (int i = blockIdx.x * blockDim.x + threadIdx.x; i < n; i += stride) {
        int p = ptr[i] + bsum[i / SCAN_BLK];
        ptr[i] = p;
        cur[i] = p;
    }
    if (blockIdx.x == 0 && threadIdx.x == 0) ptr[n] = E;
}

__global__ __launch_bounds__(256) void k_fill(const int* __restrict__ erow,
                                              const int* __restrict__ ecol,
                                              int* cur, int* __restrict__ col, int E) {
    int stride = gridDim.x * blockDim.x;
    for (int e = blockIdx.x * blockDim.x + threadIdx.x; e < E; e += stride) {
        int p = atomicAdd(&cur[erow[e]], 1);
        col[p] = ecol[e];
    }
}

// one wave per node, 4-way memory-level parallelism on the neighbor gather
__global__ __launch_bounds__(256) void k_agg(const float* __restrict__ v,
                                             const int* __restrict__ ptr,
                                             const int* __restrict__ col,
                                             const float* __restrict__ epsp,
                                             float* __restrict__ out, int n) {
    int r = (blockIdx.x * 256 + threadIdx.x) >> 6;
    int lane = threadIdx.x & 63;
    if (r >= n) return;
    float eps = epsp[0];
    float2 a = *((const float2*)(v + (size_t)r * H_DIM) + lane);
    float acx = eps * a.x, acy = eps * a.y;
    int s = ptr[r], e = ptr[r + 1];
    int i = s;
    for (; i + 4 <= e; i += 4) {
        int c0 = col[i], c1 = col[i + 1], c2 = col[i + 2], c3 = col[i + 3];
        float2 b0 = *((const float2*)(v + (size_t)c0 * H_DIM) + lane);
        float2 b1 = *((const float2*)(v + (size_t)c1 * H_DIM) + lane);
        float2 b2 = *((const float2*)(v + (size_t)c2 * H_DIM) + lane);
        float2 b3 = *((const float2*)(v + (size_t)c3 * H_DIM) + lane);
        acx += (b0.x + b1.x) + (b2.x + b3.x);
        acy += (b0.y + b1.y) + (b2.y + b3.y);
    }
    for (; i < e; i++) {
        int c = col[i];
        float2 b = *((const float2*)(v + (size_t)c * H_DIM) + lane);
        acx += b.x;
        acy += b.y;
    }
    *((float2*)(out + (size_t)r * H_DIM) + lane) = make_float2(acx, acy);
}

// ---------------- fallback atomic path ----------------

__global__ __launch_bounds__(256) void k_init(const float4* __restrict__ v4,
                                              const float* __restrict__ epsp,
                                              float4* __restrict__ out4, int n4) {
    float eps = epsp[0];
    int stride = gridDim.x * blockDim.x;
    for (int i = blockIdx.x * blockDim.x + threadIdx.x; i < n4; i += stride) {
        float4 a = v4[i];
        out4[i] = make_float4(eps * a.x, eps * a.y, eps * a.z, eps * a.w);
    }
}

__global__ __launch_bounds__(256) void k_scatter(const float* __restrict__ v,
                                                 const int* __restrict__ erow,
                                                 const int* __restrict__ ecol,
                                                 float* agg, int E) {
    int tid = blockIdx.x * blockDim.x + threadIdx.x;
    int lane = tid & 63;
    int wave = tid >> 6;
    int nwaves = (gridDim.x * blockDim.x) >> 6;
    for (int e = wave; e < E; e += nwaves) {
        int r = erow[e], c = ecol[e];
        const float2 val = *((const float2*)(v + (size_t)c * H_DIM) + lane);
        float* dst = agg + (size_t)r * H_DIM + lane * 2;
        unsafeAtomicAdd(dst, val.x);
        unsafeAtomicAdd(dst + 1, val.y);
    }
}

// ---------------- MFMA GEMM: C = [bnrelu?](A) @ W + bias, fp32 via bf16 hi/lo split ----

__device__ inline void split8(const float* xs, short8& hi, short8& lo) {
#pragma unroll
    for (int e = 0; e < 8; e++) {
        unsigned u = __float_as_uint(xs[e]);
        hi[e] = (short)(unsigned short)(u >> 16);
        float hf = __uint_as_float(u & 0xFFFF0000u);
        lo[e] = (short)(unsigned short)(__float_as_uint(xs[e] - hf) >> 16);
    }
}

template <int BN>
__global__ __launch_bounds__(256, 2) void k_gemm_mfma(
        const float* __restrict__ A, float* __restrict__ C,
        const float* __restrict__ W, const float* __restrict__ bias,
        const float* __restrict__ scl_in, const float* __restrict__ of_in,
        float* __restrict__ sums, float* __restrict__ sumsq) {
    __shared__ unsigned short Whi[128 * 136];   // 34816 B
    __shared__ unsigned short Wlo[128 * 136];   // 34816 B
    __shared__ float scof[256];                 // sc[128], of[128]
    __shared__ float stats[2][4][128];          // 4096 B

    const int t = threadIdx.x;
    const int w = t >> 6;
    const int l = t & 63;
    const int n = l & 15;       // A row-in-frag / B(=W) col-in-frag
    const int g = l >> 4;       // k-octet group
    const size_t row0 = (size_t)blockIdx.x * 128 + w * 32;

    // ---- stage W^T hi/lo (coalesced global reads, scalar LDS writes) ----
#pragma unroll 8
    for (int it = 0; it < 64; ++it) {
        int k = it * 2 + (t >> 7);
        int nn = t & 127;
        float wv = W[k * 128 + nn];
        unsigned u = __float_as_uint(wv);
        Whi[nn * 136 + k] = (unsigned short)(u >> 16);
        float hf = __uint_as_float(u & 0xFFFF0000u);
        Wlo[nn * 136 + k] = (unsigned short)(__float_as_uint(wv - hf) >> 16);
    }
    if (BN && t < 128) { scof[t] = scl_in[t]; scof[128 + t] = of_in[t]; }
    __syncthreads();

    float breg[8];
#pragma unroll
    for (int cb = 0; cb < 8; cb++) breg[cb] = bias[cb * 16 + n];

    f32x4 acc[2][8];
#pragma unroll
    for (int rf = 0; rf < 2; rf++)
#pragma unroll
        for (int cb = 0; cb < 8; cb++) acc[rf][cb] = (f32x4){0.f, 0.f, 0.f, 0.f};

    const float* Arow0 = A + (row0 + n) * H_DIM;
    const float* Arow1 = A + (row0 + 16 + n) * H_DIM;

#pragma unroll
    for (int kb = 0; kb < 4; kb++) {
        const int k0 = kb * 32 + g * 8;
        float4 x00 = *(const float4*)(Arow0 + k0);
        float4 x01 = *(const float4*)(Arow0 + k0 + 4);
        float4 x10 = *(const float4*)(Arow1 + k0);
        float4 x11 = *(const float4*)(Arow1 + k0 + 4);
        float xs0[8] = {x00.x, x00.y, x00.z, x00.w, x01.x, x01.y, x01.z, x01.w};
        float xs1[8] = {x10.x, x10.y, x10.z, x10.w, x11.x, x11.y, x11.z, x11.w};
        if (BN) {
            float sc[8], of[8];
            float4 sa = *(const float4*)(scof + k0);
            float4 sb = *(const float4*)(scof + k0 + 4);
            float4 oa = *(const float4*)(scof + 128 + k0);
            float4 ob = *(const float4*)(scof + 128 + k0 + 4);
            sc[0] = sa.x; sc[1] = sa.y; sc[2] = sa.z; sc[3] = sa.w;
            sc[4] = sb.x; sc[5] = sb.y; sc[6] = sb.z; sc[7] = sb.w;
            of[0] = oa.x; of[1] = oa.y; of[2] = oa.z; of[3] = oa.w;
            of[4] = ob.x; of[5] = ob.y; of[6] = ob.z; of[7] = ob.w;
#pragma unroll
            for (int e = 0; e < 8; e++) {
                xs0[e] = fmaxf(fmaf(xs0[e], sc[e], of[e]), 0.f);
                xs1[e] = fmaxf(fmaf(xs1[e], sc[e], of[e]), 0.f);
            }
        }
        short8 ah0, al0, ah1, al1;
        split8(xs0, ah0, al0);
        split8(xs1, ah1, al1);

        short8 wh[8], wl[8];
        const int wb = n * 136 + kb * 32 + g * 8;
#pragma unroll
        for (int cb = 0; cb < 8; cb++) {
            wh[cb] = *(const short8*)(Whi + cb * 2176 + wb);
            wl[cb] = *(const short8*)(Wlo + cb * 2176 + wb);
        }
#pragma unroll
        for (int cb = 0; cb < 8; cb++) {
            acc[0][cb] = __builtin_amdgcn_mfma_f32_16x16x32_bf16(ah0, wh[cb], acc[0][cb], 0, 0, 0);
            acc[1][cb] = __builtin_amdgcn_mfma_f32_16x16x32_bf16(ah1, wh[cb], acc[1][cb], 0, 0, 0);
            acc[0][cb] = __builtin_amdgcn_mfma_f32_16x16x32_bf16(al0, wh[cb], acc[0][cb], 0, 0, 0);
            acc[1][cb] = __builtin_amdgcn_mfma_f32_16x16x32_bf16(al1, wh[cb], acc[1][cb], 0, 0, 0);
            acc[0][cb] = __builtin_amdgcn_mfma_f32_16x16x32_bf16(ah0, wl[cb], acc[0][cb], 0, 0, 0);
            acc[1][cb] = __builtin_amdgcn_mfma_f32_16x16x32_bf16(ah1, wl[cb], acc[1][cb], 0, 0, 0);
        }
    }

    // epilogue: bias add, store, per-column stats
    float s[8], s2[8];
#pragma unroll
    for (int cb = 0; cb < 8; cb++) { s[cb] = 0.f; s2[cb] = 0.f; }
#pragma unroll
    for (int cb = 0; cb < 8; cb++) {
        const int c = cb * 16 + n;
#pragma unroll
        for (int rf = 0; rf < 2; rf++) {
            f32x4 o = acc[rf][cb];
            const size_t rbase = (row0 + rf * 16 + g * 4) * H_DIM + c;
#pragma unroll
            for (int r = 0; r < 4; r++) {
                float val = o[r] + breg[cb];
                C[rbase + (size_t)r * H_DIM] = val;
                s[cb] += val;
                s2[cb] += val * val;
            }
        }
    }
#pragma unroll
    for (int cb = 0; cb < 8; cb++) {
        s[cb] += __shfl_xor(s[cb], 16, 64);
        s[cb] += __shfl_xor(s[cb], 32, 64);
        s2[cb] += __shfl_xor(s2[cb], 16, 64);
        s2[cb] += __shfl_xor(s2[cb], 32, 64);
    }
    if (g == 0) {
#pragma unroll
        for (int cb = 0; cb < 8; cb++) {
            stats[0][w][cb * 16 + n] = s[cb];
            stats[1][w][cb * 16 + n] = s2[cb];
        }
    }
    __syncthreads();
    if (t < 128) {
        float S  = stats[0][0][t] + stats[0][1][t] + stats[0][2][t] + stats[0][3][t];
        float S2 = stats[1][0][t] + stats[1][1][t] + stats[1][2][t] + stats[1][3][t];
        unsafeAtomicAdd(sums + t, S);
        unsafeAtomicAdd(sumsq + t, S2);
    }
}

__global__ void k_finalize(const float* __restrict__ sums, const float* __restrict__ sumsq,
                           float* __restrict__ mean, float* __restrict__ scl,
                           float* __restrict__ of,
                           const float* __restrict__ g, const float* __restrict__ beta,
                           float invN) {
    int t = threadIdx.x;
    if (t < H_DIM) {
        float m = sums[t] * invN;
        float var = sumsq[t] * invN - m * m;
        float sc = g[t] * rsqrtf(var + 1e-5f);
        mean[t] = m;
        scl[t] = sc;
        of[t] = beta[t] - m * sc;
    }
}

// ---------------- merged final bn+relu (blocks 1..G-1) + random walk (block 0) ----

__device__ inline float block_max4(float v, int t, float* s_r) {
#pragma unroll
    for (int m = 1; m < 64; m <<= 1) v = fmaxf(v, __shfl_xor(v, m, 64));
    if ((t & 63) == 0) s_r[t >> 6] = v;
    __syncthreads();
    float r = fmaxf(fmaxf(s_r[0], s_r[1]), fmaxf(s_r[2], s_r[3]));
    __syncthreads();
    return r;
}

__device__ inline float block_sum4(float v, int t, float* s_r) {
#pragma unroll
    for (int m = 1; m < 64; m <<= 1) v += __shfl_xor(v, m, 64);
    if ((t & 63) == 0) s_r[t >> 6] = v;
    __syncthreads();
    float r = (s_r[0] + s_r[1]) + (s_r[2] + s_r[3]);
    __syncthreads();
    return r;
}

// argmax, ties -> smaller index (matches jnp.argmax)
__device__ inline void block_argmax4(float v, int idx, int t, float* s_rv, int* s_ri,
                                     float* outv, int* outi) {
#pragma unroll
    for (int m = 1; m < 64; m <<= 1) {
        float ov = __shfl_xor(v, m, 64);
        int oi = __shfl_xor(idx, m, 64);
        if (ov > v || (ov == v && oi < idx)) { v = ov; idx = oi; }
    }
    if ((t & 63) == 0) { s_rv[t >> 6] = v; s_ri[t >> 6] = idx; }
    __syncthreads();
    float bv = s_rv[0];
    int bi = s_ri[0];
#pragma unroll
    for (int j = 1; j < 4; j++) {
        float ov = s_rv[j];
        int oi = s_ri[j];
        if (ov > bv || (ov == bv && oi < bi)) { bv = ov; bi = oi; }
    }
    *outv = bv;
    *outi = bi;
    __syncthreads();
}

__global__ __launch_bounds__(256) void k_bnwalk(
        float4* y4, const float* __restrict__ scl, const float* __restrict__ of, int n4,
        const int* __restrict__ adj, const float* __restrict__ scores,
        const float* __restrict__ feats, const int* __restrict__ perm,
        const float* __restrict__ xs, float* __restrict__ outw) {
    __shared__ int s_adj[NB_ * NB_];
    __shared__ float s_scores[NB_], s_soft[NB_];
    __shared__ int s_perm[P_];
    __shared__ unsigned char s_inperm[NB_], s_sel[NB_], s_allvis[NB_], s_vis[NB_];
    __shared__ int s_starts[NSTART_];
    __shared__ int s_path[MAXLEN_];
    __shared__ unsigned char s_valid[MAXLEN_];
    __shared__ float s_w[MAXLEN_];
    __shared__ int s_cur, s_alive, s_do, s_idx, s_skip;
    __shared__ float s_rv[4];
    __shared__ int s_ri[4];

    const int t = threadIdx.x;

    if (blockIdx.x != 0) {
        // ---- streaming bn+relu over the GIN output ----
        int stride = (gridDim.x - 1) * 256;
        for (int i = (blockIdx.x - 1) * 256 + t; i < n4; i += stride) {
            int c = (i & 31) * 4;
            float4 a = y4[i];
            a.x = fmaxf(fmaf(a.x, scl[c + 0], of[c + 0]), 0.f);
            a.y = fmaxf(fmaf(a.y, scl[c + 1], of[c + 1]), 0.f);
            a.z = fmaxf(fmaf(a.z, scl[c + 2], of[c + 2]), 0.f);
            a.w = fmaxf(fmaf(a.w, scl[c + 3], of[c + 3]), 0.f);
            y4[i] = a;
        }
        return;
    }

    // ---- block 0: biased random walk ----
    for (int i = t; i < P_ * H_DIM; i += 256) outw[i] = xs[i];
    for (int i = t; i < NB_ * NB_; i += 256) s_adj[i] = adj[i];
    if (t < P_) s_perm[t] = perm[t];
    if (t < NB_) { s_scores[t] = scores[t]; s_allvis[t] = 0; s_sel[t] = 0; }
    __syncthreads();
    if (t < NB_) {
        unsigned char inp = 0;
        for (int j = 0; j < P_; j++) inp |= (s_perm[j] == t) ? 1 : 0;
        s_inperm[t] = inp;
    }
    __syncthreads();

    float myv = (t < NB_) ? s_scores[t] : -INFINITY;
    float mx = block_max4(myv, t, s_rv);
    float e = (t < NB_) ? expf(s_scores[t] - mx) : 0.f;
    float ssum = block_sum4(e, t, s_rv);
    if (t < NB_) s_soft[t] = e / ssum;

    float ninf = block_sum4((t < NB_ && s_inperm[t]) ? 1.f : 0.f, t, s_rv);
    int nin = (int)(ninf + 0.5f);
    int nok = nin < NSTART_ ? nin : NSTART_;
    __syncthreads();

    for (int r = 0; r < NSTART_; r++) {
        bool useIn = (r < nin);
        bool elig = (t < NB_) && !s_sel[t] && (((s_inperm[t] != 0)) == useIn);
        float v = elig ? s_scores[t] : -INFINITY;
        float mv; int mi;
        block_argmax4(v, elig ? t : 0x7fffffff, t, s_rv, s_ri, &mv, &mi);
        if (t == 0) s_starts[r] = mi;
        if (t == mi && t < NB_) s_sel[t] = 1;
        __syncthreads();
    }

    for (int s = 0; s < NSTART_; s++) {
        if (t == 0) {
            int start = s_starts[s];
            int ok = (s < nok) ? 1 : 0;
            int skip = (!ok) || s_allvis[start];
            s_skip = skip;
            s_cur = start;
            s_alive = 1;
            s_path[0] = start;
            s_valid[0] = 1;
            int idx = 0, found = 0;
            for (int j = 0; j < P_; j++)
                if (!found && s_perm[j] == start) { idx = j; found = 1; }
            s_idx = idx;
            s_do = (!skip) && found;
        }
        __syncthreads();
        if (t < NB_) s_vis[t] = s_allvis[t];
        __syncthreads();
        if (t == 0) s_vis[s_cur] = 1;
        __syncthreads();

        for (int st = 1; st < MAXLEN_; st++) {
            int cur = s_cur;
            int alive = s_alive;
            bool elig = (t < NB_) && alive && (s_adj[cur * NB_ + t] > 0) && (!s_vis[t]);
            float v = elig ? s_soft[t] : -INFINITY;
            float mv; int mi;
            block_argmax4(v, elig ? t : 0x7fffffff, t, s_rv, s_ri, &mv, &mi);
            if (t == 0) {
                int has = (mv > -INFINITY) ? 1 : 0;
                if (has) { s_cur = mi; s_vis[mi] = 1; }
                s_path[st] = has ? mi : cur;
                s_valid[st] = (unsigned char)has;
                s_alive = has;
            }
            __syncthreads();
        }

        if (t == 0) {
            float mxw = -INFINITY;
            for (int st = 0; st < MAXLEN_; st++)
                if (s_valid[st]) mxw = fmaxf(mxw, s_scores[s_path[st]]);
            float sw = 0.f;
            for (int st = 0; st < MAXLEN_; st++) {
                float ev = s_valid[st] ? expf(s_scores[s_path[st]] - mxw) : 0.f;
                s_w[st] = ev; sw += ev;
            }
            float inv = 1.f / sw;
            for (int st = 0; st < MAXLEN_; st++) s_w[st] *= inv;
        }
        __syncthreads();
        if (s_do && t < H_DIM) {
            float acc = 0.f;
            for (int st = 0; st < MAXLEN_; st++)
                acc += s_w[st] * feats[s_path[st] * H_DIM + t];
            outw[s_idx * H_DIM + t] += acc;
        }
        __syncthreads();
        if (!s_skip && t < NB_) s_allvis[t] = s_vis[t];
        __syncthreads();
    }
}

// ---------------- launch ----------------

extern "C" void kernel_launch(void* const* d_in, const int* in_sizes, int n_in,
                              void* d_out, int out_size, void* d_ws, size_t ws_size,
                              hipStream_t stream) {
    const float* v    = (const float*)d_in[0];
    const int*   erow = (const int*)d_in[1];
    const int*   ecol = (const int*)d_in[2];
    const float* W1   = (const float*)d_in[3];
    const float* b1   = (const float*)d_in[4];
    const float* g1   = (const float*)d_in[5];
    const float* be1  = (const float*)d_in[6];
    const float* W2   = (const float*)d_in[7];
    const float* b2   = (const float*)d_in[8];
    const float* g2   = (const float*)d_in[9];
    const float* be2  = (const float*)d_in[10];
    const float* epsp = (const float*)d_in[11];
    const int*   adj  = (const int*)d_in[12];
    const float* scr  = (const float*)d_in[13];
    const float* fts  = (const float*)d_in[14];
    const int*   perm = (const int*)d_in[15];
    const float* xs   = (const float*)d_in[16];

    float* out = (float*)d_out;
    float* wsf = (float*)d_ws;
    float* sums1 = wsf,        *sumsq1 = wsf + 128,  *mean1 = wsf + 256,  *scl1 = wsf + 384,  *of1 = wsf + 512;
    float* sums2 = wsf + 640,  *sumsq2 = wsf + 768,  *mean2 = wsf + 896,  *scl2 = wsf + 1024, *of2 = wsf + 1152;

    const int E  = in_sizes[1];
    const int N  = N_NODES;
    const int n4 = NH / 4;

    int* ws_i = (int*)(wsf + 1280);
    int* cnt  = ws_i;                   // N+1
    int* ptr  = ws_i + (N + 1);         // N+1
    int* cur  = ws_i + 2 * (N + 1);     // N
    int* col  = ws_i + 3 * (N + 1);     // E
    size_t need = 1280 * 4 + (size_t)(3 * (N + 1) + E) * 4;

    if (ws_size >= need) {
        const int nb = (N + SCAN_BLK - 1) / SCAN_BLK;   // 222
        k_zero<<<512, 256, 0, stream>>>(wsf, cnt, N + 1);
        k_hist<<<1024, 256, 0, stream>>>(erow, cnt, E);
        k_scan1<<<nb, 256, 0, stream>>>(cnt, ptr, cur /*tmp bsum*/, N);
        k_scan2<<<1, 256, 0, stream>>>(cur, nb);
        k_scan3<<<512, 256, 0, stream>>>(ptr, cur, cnt /*becomes fill cursors*/, N, E);
        k_fill<<<1024, 256, 0, stream>>>(erow, ecol, cnt, col, E);
        k_agg<<<N / 4, 256, 0, stream>>>(v, ptr, col, epsp, out, N);
    } else {
        k_zero<<<512, 256, 0, stream>>>(wsf, cnt, 0);
        k_init<<<2048, 256, 0, stream>>>((const float4*)v, epsp, (float4*)out, n4);
        k_scatter<<<4096, 256, 0, stream>>>(v, erow, ecol, out, E);
    }

    k_gemm_mfma<0><<<N / 128, 256, 0, stream>>>(out, out, W1, b1, nullptr, nullptr,
                                                sums1, sumsq1);
    k_finalize<<<1, 128, 0, stream>>>(sums1, sumsq1, mean1, scl1, of1, g1, be1, 1.f / N);
    k_gemm_mfma<1><<<N / 128, 256, 0, stream>>>(out, out, W2, b2, scl1, of1,
                                                sums2, sumsq2);
    k_finalize<<<1, 128, 0, stream>>>(sums2, sumsq2, mean2, scl2, of2, g2, be2, 1.f / N);
    k_bnwalk<<<2049, 256, 0, stream>>>((float4*)out, scl2, of2, n4,
                                       adj, scr, fts, perm, xs, out + NH);
}